// Round 7
// baseline (599.909 us; speedup 1.0000x reference)
//
#include <hip/hip_runtime.h>

typedef __bf16 bf16;
typedef __bf16 bf16x4 __attribute__((ext_vector_type(4)));
typedef __bf16 bf16x8 __attribute__((ext_vector_type(8)));
typedef float f32x4 __attribute__((ext_vector_type(4)));
typedef float floatx4 __attribute__((ext_vector_type(4)));

#define S 96
#define DIN 768
#define DOUT 256
#define MROWS 73728  // 8*96*96

__device__ static inline void async16(const bf16* g, bf16* l) {
    __builtin_amdgcn_global_load_lds(
        (const __attribute__((address_space(1))) void*)g,
        (__attribute__((address_space(3))) void*)l,
        16, 0, 0);
}

// ---------------------------------------------------------------------------
// GEMM1: P0[M x 768] = table @ W1T^T (bf16 compute, fp32 A input).
// 256x256/BK=64, 8 waves, counted vmcnt, chunk-XOR swizzle. The fp32->bf16
// cast of the table is FUSED into A-staging (reg-stage: 2x f32x4 load, cvt,
// ds_write_b128), eliminating the standalone k_cast kernel (339 MB traffic).
// LDS layout identical to the async version: LDS[row][c]=global[row][c^(row&7)]
// so the read-side swizzle addressing is unchanged. B stays global_load_lds.
// Staging spread over phases keeps <=16 staging VGPRs in flight.
// ---------------------------------------------------------------------------
__global__ __launch_bounds__(512, 2) void k_gemm1(
    const float* __restrict__ X0, const bf16* __restrict__ WT,
    bf16* __restrict__ Y)
{
    constexpr int K = 768, N = 768;
    constexpr int NTILE = K / 64;  // 12
    __shared__ __align__(16) bf16 As[2][256 * 64];
    __shared__ __align__(16) bf16 Bs[2][256 * 64];
    int t = threadIdx.x;
    int wg = blockIdx.x;
    wg = (wg & 7) * (gridDim.x >> 3) + (wg >> 3);  // 864 = 8*108: bijective
    int colBase = (wg % 3) * 256;                  // col fastest within XCD
    int rowBase = (wg / 3) * 256;
    int lane = t & 63, w = t >> 6;
    int quad = lane >> 4, l16 = lane & 15;
    int wr = w >> 2, wc = w & 3;                   // 2 x 4 waves

    floatx4 acc[8][4];
#pragma unroll
    for (int i = 0; i < 8; ++i)
#pragma unroll
        for (int j = 0; j < 4; ++j) acc[i][j] = (floatx4)0.f;

    // thread t -> row tr (within 64-row sub-stage s), LDS chunk (t&7);
    // global chunk pre-swizzled gc = (t&7) ^ (row&7).
    int tr = t >> 3;
    int gc = (t & 7) ^ (tr & 7);
    const float* gA = X0 + (size_t)(rowBase + tr) * K + gc * 8;   // fp32!
    const bf16*  gB = WT + (size_t)(colBase + tr) * K + gc * 8;
    int ldst = t * 8;

    auto loadA = [&](int s, int kt, f32x4& lo, f32x4& hi) {
        const float* p = gA + (size_t)s * 64 * K + kt * 64;
        lo = *(const f32x4*)p;
        hi = *(const f32x4*)(p + 4);
    };
    auto writeA = [&](int b, int s, f32x4 lo, f32x4 hi) {
        bf16x8 o;
#pragma unroll
        for (int j = 0; j < 4; ++j) { o[j] = (bf16)lo[j]; o[4 + j] = (bf16)hi[j]; }
        *(bf16x8*)&As[b][s * 4096 + ldst] = o;
    };
    auto stageB = [&](int b, int s, int kt) {
        async16(gB + (size_t)s * 64 * K + kt * 64, &Bs[b][s * 4096 + ldst]);
    };

    // prologue: tile 0 into buf 0 (<=16 staging VGPRs at a time)
    {
        f32x4 r0lo, r0hi, r1lo, r1hi;
        loadA(0, 0, r0lo, r0hi); loadA(1, 0, r1lo, r1hi);
        asm volatile("s_waitcnt vmcnt(0)" ::: "memory");
        writeA(0, 0, r0lo, r0hi); writeA(0, 1, r1lo, r1hi);
        loadA(2, 0, r0lo, r0hi); loadA(3, 0, r1lo, r1hi);
        stageB(0, 0, 0); stageB(0, 1, 0); stageB(0, 2, 0); stageB(0, 3, 0);
        asm volatile("s_waitcnt vmcnt(4)" ::: "memory");
        writeA(0, 2, r0lo, r0hi); writeA(0, 3, r1lo, r1hi);
    }
    __syncthreads();

    int swz = l16 & 7;
    int cK0 = (quad ^ swz) * 8;
    int cK1 = ((quad + 4) ^ swz) * 8;

    for (int tt = 0; tt < NTILE; ++tt) {
        int cur = tt & 1;
        int nb = cur ^ 1;
        bool more = (tt + 1 < NTILE);
        const bf16* aB = &As[cur][(wr * 128 + l16) * 64];
        const bf16* bB = &Bs[cur][(wc * 64 + l16) * 64];
        f32x4 r0lo, r0hi, r1lo, r1hi;
#pragma unroll
        for (int p = 0; p < 4; ++p) {
            const int ihalf = p & 1;
            const int co = (p >> 1) ? cK1 : cK0;
            bf16x8 af[4], bfr[4];
#pragma unroll
            for (int ii = 0; ii < 4; ++ii)
                af[ii] = *(const bf16x8*)(aB + (ihalf * 4 + ii) * 1024 + co);
#pragma unroll
            for (int j = 0; j < 4; ++j)
                bfr[j] = *(const bf16x8*)(bB + j * 1024 + co);
            if (more) {
                if (p == 0) { loadA(0, tt + 1, r0lo, r0hi); loadA(1, tt + 1, r1lo, r1hi); }
                if (p == 1) { writeA(nb, 0, r0lo, r0hi); writeA(nb, 1, r1lo, r1hi);
                              loadA(2, tt + 1, r0lo, r0hi); loadA(3, tt + 1, r1lo, r1hi); }
                if (p == 2) { writeA(nb, 2, r0lo, r0hi); writeA(nb, 3, r1lo, r1hi);
                              stageB(nb, 0, tt + 1); stageB(nb, 1, tt + 1);
                              stageB(nb, 2, tt + 1); stageB(nb, 3, tt + 1); }
            }
            __builtin_amdgcn_s_barrier();
            asm volatile("s_waitcnt lgkmcnt(0)" ::: "memory");
            __builtin_amdgcn_sched_barrier(0);
            __builtin_amdgcn_s_setprio(1);
#pragma unroll
            for (int ii = 0; ii < 4; ++ii)
#pragma unroll
                for (int j = 0; j < 4; ++j)
                    acc[ihalf * 4 + ii][j] = __builtin_amdgcn_mfma_f32_16x16x32_bf16(
                        af[ii], bfr[j], acc[ihalf * 4 + ii][j], 0, 0, 0);
            __builtin_amdgcn_s_setprio(0);
            if (more) {
                if (p == 0) asm volatile("s_waitcnt vmcnt(0)" ::: "memory"); // A s0,s1
                if (p == 1) asm volatile("s_waitcnt vmcnt(0)" ::: "memory"); // A s2,s3
            }
            if (p == 3) asm volatile("s_waitcnt vmcnt(0)" ::: "memory");     // B asyncs
            __builtin_amdgcn_s_barrier();
        }
    }

#pragma unroll
    for (int i = 0; i < 8; ++i) {
#pragma unroll
        for (int r = 0; r < 4; ++r) {
            int row = rowBase + wr * 128 + i * 16 + quad * 4 + r;
            bf16* yp = Y + (size_t)row * N + colBase + wc * 64 + l16;
#pragma unroll
            for (int j = 0; j < 4; ++j)
                yp[j * 16] = (bf16)acc[i][j][r];
        }
    }
}

// ---------------------------------------------------------------------------
// gn1: h1 = relu(g1 * t5norm((2I+G')P0 + b1)). One (b,l,half) per block;
// each wave owns whole rows (768 elems = 12 f32/lane), ssq via shuffle
// reduce, norm+relu+cast in the same pass.
// ---------------------------------------------------------------------------
__global__ __launch_bounds__(256) void k_gn1(
    const bf16* __restrict__ P, const float* __restrict__ G1,
    const float* __restrict__ B1, const float* __restrict__ Asim,
    const float* __restrict__ Tsim, const float* __restrict__ Adj,
    bf16* __restrict__ O)
{
    __shared__ float adjs[S];
    __shared__ float ts[S];
    __shared__ float diagf[DIN];
    __shared__ float g1s[DIN];
    __shared__ float b1s[DIN];
    int bx = blockIdx.x;
    bx = (bx & 7) * (gridDim.x >> 3) + (bx >> 3);  // 768 % 8 == 0
    int b = bx / S, l = bx % S;
    int tid = threadIdx.x;
    long row0 = (long)(b * S + l) * S;
    for (int i = tid; i < DIN; i += 256) { g1s[i] = G1[i]; b1s[i] = B1[i]; }
    if (tid < S) {
        adjs[tid] = Adj[(b * S + l) * S + tid];
        ts[tid]   = Tsim[b * S + tid];
        bf16x8 dv = *(const bf16x8*)&P[(row0 + l) * DIN + tid * 8];
#pragma unroll
        for (int j = 0; j < 8; ++j) diagf[tid * 8 + j] = (float)dv[j];
    }
    float a_up = (l > 0)     ? Asim[b * S + l - 1] : 0.f;
    float a_dn = (l < S - 1) ? Asim[b * S + l + 1] : 0.f;
    long du = (l > 0)     ? -(long)S * DIN : 0;
    long dd = (l < S - 1) ?  (long)S * DIN : 0;
    __syncthreads();

    int lane = tid & 63, wv = tid >> 6;
    int k0 = blockIdx.y * (S / 2);
    for (int k = k0 + wv; k < k0 + S / 2; k += 4) {
        float tl = (k > 0)     ? ts[k - 1] : 0.f;
        float tr = (k < S - 1) ? ts[k + 1] : 0.f;
        long  dl = (k > 0)     ? -(long)DIN : 0;
        long  dr = (k < S - 1) ?  (long)DIN : 0;
        float aj = adjs[k];
        const bf16* prow = P + (row0 + k) * DIN;
        bf16* orow = O + (row0 + k) * DIN;
        float v[12];
        float ss = 0.f;
#pragma unroll
        for (int c = 0; c < 3; ++c) {
            int col = (lane + c * 64) * 4;
            const bf16* pc = prow + col;
            bf16x4 vc = *(const bf16x4*)pc;
            bf16x4 vl = *(const bf16x4*)(pc + dl);
            bf16x4 vr = *(const bf16x4*)(pc + dr);
            bf16x4 vu = *(const bf16x4*)(pc + du);
            bf16x4 vd = *(const bf16x4*)(pc + dd);
#pragma unroll
            for (int j = 0; j < 4; ++j) {
                float x = 2.f * (float)vc[j] + aj * diagf[col + j]
                        + tl * (float)vl[j] + tr * (float)vr[j]
                        + a_up * (float)vu[j] + a_dn * (float)vd[j]
                        + b1s[col + j];
                v[c * 4 + j] = x;
                ss += x * x;
            }
        }
        ss += __shfl_xor(ss, 1);
        ss += __shfl_xor(ss, 2);
        ss += __shfl_xor(ss, 4);
        ss += __shfl_xor(ss, 8);
        ss += __shfl_xor(ss, 16);
        ss += __shfl_xor(ss, 32);
        float inv = rsqrtf(ss * (1.f / DIN) + 1e-12f);
#pragma unroll
        for (int c = 0; c < 3; ++c) {
            int col = (lane + c * 64) * 4;
            bf16x4 o;
#pragma unroll
            for (int j = 0; j < 4; ++j) {
                float y = v[c * 4 + j] * g1s[col + j] * inv;
                o[j] = (bf16)(y > 0.f ? y : 0.f);
            }
            *(bf16x4*)&orow[col] = o;
        }
    }
}

// ---------------------------------------------------------------------------
// GEMM2: P1[M x 256] = h1 @ W2T^T (bf16, plain — norm moved to gn2).
// 128 rows x 256 cols per block; 3-buf counted vmcnt.
// ---------------------------------------------------------------------------
__global__ __launch_bounds__(256, 2) void k_gemm2(
    const bf16* __restrict__ Xm, const bf16* __restrict__ WT,
    bf16* __restrict__ Y)
{
    constexpr int K = 768, N = 256;
    constexpr int NT = K / 32;  // 24
    __shared__ __align__(16) bf16 As[3][128 * 32];
    __shared__ __align__(16) bf16 Bs[3][256 * 32];
    int t = threadIdx.x;
    int rowBase = blockIdx.x * 128;
    int lane = t & 63, w = t >> 6;
    int quad = lane >> 4, l16 = lane & 15;
    int wr = w >> 1, wc = w & 1;

    floatx4 acc[4][8];
#pragma unroll
    for (int i = 0; i < 4; ++i)
#pragma unroll
        for (int j = 0; j < 8; ++j) acc[i][j] = (floatx4)0.f;

    int chunk = (t & 3) ^ ((t >> 3) & 3);
    const bf16* gA = Xm + (size_t)(rowBase + (t >> 2)) * K + chunk * 8;
    const bf16* gB = WT + (size_t)(t >> 2) * K + chunk * 8;
    int l8 = t * 8;

    auto stage = [&](int buf, int kk) {
        async16(gA + kk, &As[buf][l8]);
        async16(gA + kk + 64 * K, &As[buf][l8 + 2048]);
        async16(gB + kk, &Bs[buf][l8]);
        async16(gB + kk + 64 * K, &Bs[buf][l8 + 2048]);
        async16(gB + kk + 128 * K, &Bs[buf][l8 + 4096]);
        async16(gB + kk + 192 * K, &Bs[buf][l8 + 6144]);
    };

    stage(0, 0);
    stage(1, 32);
    for (int tt = 0; tt < NT; ++tt) {
        if (tt + 1 < NT) asm volatile("s_waitcnt vmcnt(6)" ::: "memory");
        else             asm volatile("s_waitcnt vmcnt(0)" ::: "memory");
        __builtin_amdgcn_s_barrier();
        int cur = tt % 3;
        bf16x8 af[4], bfr[8];
#pragma unroll
        for (int i = 0; i < 4; ++i) {
            int ra = wr * 64 + i * 16 + l16;
            af[i] = *(const bf16x8*)&As[cur][ra * 32 + (quad ^ ((ra >> 1) & 3)) * 8];
        }
#pragma unroll
        for (int j = 0; j < 8; ++j) {
            int rb = wc * 128 + j * 16 + l16;
            bfr[j] = *(const bf16x8*)&Bs[cur][rb * 32 + (quad ^ ((rb >> 1) & 3)) * 8];
        }
        if (tt + 2 < NT) stage((tt + 2) % 3, (tt + 2) * 32);
#pragma unroll
        for (int i = 0; i < 4; ++i)
#pragma unroll
            for (int j = 0; j < 8; ++j)
                acc[i][j] = __builtin_amdgcn_mfma_f32_16x16x32_bf16(
                    af[i], bfr[j], acc[i][j], 0, 0, 0);
    }

#pragma unroll
    for (int i = 0; i < 4; ++i) {
#pragma unroll
        for (int r = 0; r < 4; ++r) {
            int row = rowBase + wr * 64 + i * 16 + quad * 4 + r;
            bf16* yp = Y + (size_t)row * N + wc * 128 + l16;
#pragma unroll
            for (int j = 0; j < 8; ++j)
                yp[j * 16] = (bf16)acc[i][j][r];
        }
    }
}

// ---------------------------------------------------------------------------
// gn2: out = relu(g2 * t5norm((2I+G')P1 + b2)), fp32 out. D=256: 4 f32/lane.
// ---------------------------------------------------------------------------
__global__ __launch_bounds__(256) void k_gn2(
    const bf16* __restrict__ P, const float* __restrict__ G2,
    const float* __restrict__ B2, const float* __restrict__ Asim,
    const float* __restrict__ Tsim, const float* __restrict__ Adj,
    float* __restrict__ O)
{
    __shared__ float adjs[S];
    __shared__ float ts[S];
    __shared__ float diagf[DOUT];
    __shared__ float g2s[DOUT];
    __shared__ float b2s[DOUT];
    int bx = blockIdx.x;
    bx = (bx & 7) * (gridDim.x >> 3) + (bx >> 3);
    int b = bx / S, l = bx % S;
    int tid = threadIdx.x;
    long row0 = (long)(b * S + l) * S;
    if (tid < DOUT) { g2s[tid] = G2[tid]; b2s[tid] = B2[tid]; }
    if (tid < S) {
        adjs[tid] = Adj[(b * S + l) * S + tid];
        ts[tid]   = Tsim[b * S + tid];
    }
    if (tid < 32) {
        bf16x8 dv = *(const bf16x8*)&P[(row0 + l) * DOUT + tid * 8];
#pragma unroll
        for (int j = 0; j < 8; ++j) diagf[tid * 8 + j] = (float)dv[j];
    }
    float a_up = (l > 0)     ? Asim[b * S + l - 1] : 0.f;
    float a_dn = (l < S - 1) ? Asim[b * S + l + 1] : 0.f;
    long du = (l > 0)     ? -(long)S * DOUT : 0;
    long dd = (l < S - 1) ?  (long)S * DOUT : 0;
    __syncthreads();

    int lane = tid & 63, wv = tid >> 6;
    int k0 = blockIdx.y * (S / 2);
    for (int k = k0 + wv; k < k0 + S / 2; k += 4) {
        float tl = (k > 0)     ? ts[k - 1] : 0.f;
        float tr = (k < S - 1) ? ts[k + 1] : 0.f;
        long  dl = (k > 0)     ? -(long)DOUT : 0;
        long  dr = (k < S - 1) ?  (long)DOUT : 0;
        float aj = adjs[k];
        const bf16* prow = P + (row0 + k) * DOUT;
        float* orow = O + (row0 + k) * DOUT;
        int col = lane * 4;
        const bf16* pc = prow + col;
        bf16x4 vc = *(const bf16x4*)pc;
        bf16x4 vl = *(const bf16x4*)(pc + dl);
        bf16x4 vr = *(const bf16x4*)(pc + dr);
        bf16x4 vu = *(const bf16x4*)(pc + du);
        bf16x4 vd = *(const bf16x4*)(pc + dd);
        float v[4];
        float ss = 0.f;
#pragma unroll
        for (int j = 0; j < 4; ++j) {
            float x = 2.f * (float)vc[j] + aj * diagf[col + j]
                    + tl * (float)vl[j] + tr * (float)vr[j]
                    + a_up * (float)vu[j] + a_dn * (float)vd[j]
                    + b2s[col + j];
            v[j] = x;
            ss += x * x;
        }
        ss += __shfl_xor(ss, 1);
        ss += __shfl_xor(ss, 2);
        ss += __shfl_xor(ss, 4);
        ss += __shfl_xor(ss, 8);
        ss += __shfl_xor(ss, 16);
        ss += __shfl_xor(ss, 32);
        float inv = rsqrtf(ss * (1.f / DOUT) + 1e-12f);
        f32x4 o;
#pragma unroll
        for (int j = 0; j < 4; ++j) {
            float y = v[j] * g2s[col + j] * inv;
            o[j] = y > 0.f ? y : 0.f;
        }
        *(f32x4*)&orow[col] = o;
    }
}

// tiled transpose + cast: in fp32 [R][C] -> out bf16 [C][R]; grid (C/32, R/32)
__global__ __launch_bounds__(256) void k_castT(
    const float* __restrict__ in, bf16* __restrict__ out, int R, int C)
{
    __shared__ float tile[32][33];
    int lx = threadIdx.x & 31, ly = threadIdx.x >> 5;
    int c0 = blockIdx.x * 32, r0 = blockIdx.y * 32;
#pragma unroll
    for (int k = 0; k < 4; ++k)
        tile[ly + 8 * k][lx] = in[(size_t)(r0 + ly + 8 * k) * C + c0 + lx];
    __syncthreads();
#pragma unroll
    for (int k = 0; k < 4; ++k)
        out[(size_t)(c0 + ly + 8 * k) * R + r0 + lx] = (bf16)tile[lx][ly + 8 * k];
}

// ---------------------------------------------------------------------------
extern "C" void kernel_launch(void* const* d_in, const int* in_sizes, int n_in,
                              void* d_out, int out_size, void* d_ws, size_t ws_size,
                              hipStream_t stream)
{
    const float* table = (const float*)d_in[0];
    const float* asim  = (const float*)d_in[1];
    const float* tsim  = (const float*)d_in[2];
    const float* adj   = (const float*)d_in[3];
    const float* W1    = (const float*)d_in[4];
    const float* b1    = (const float*)d_in[5];
    const float* g1    = (const float*)d_in[6];
    const float* W2    = (const float*)d_in[7];
    const float* b2    = (const float*)d_in[8];
    const float* g2    = (const float*)d_in[9];
    float* out = (float*)d_out;

    char* ws = (char*)d_ws;
    const size_t SZ_X = (size_t)MROWS * DIN * 2;          // 113246208 bytes
    bf16*  A    = (bf16*)ws;                               // h1
    bf16*  Bb   = (bf16*)(ws + SZ_X);                      // P0, later P1
    bf16*  W1T  = (bf16*)(ws + 2 * SZ_X);
    bf16*  W2T  = (bf16*)(ws + 2 * SZ_X + 1179648);

    k_castT<<<dim3(DIN / 32, DIN / 32), 256, 0, stream>>>(W1, W1T, DIN, DIN);
    k_castT<<<dim3(DOUT / 32, DIN / 32), 256, 0, stream>>>(W2, W2T, DIN, DOUT);

    k_gemm1<<<dim3((DIN / 256) * (MROWS / 256)), 512, 0, stream>>>(table, W1T, Bb);
    k_gn1<<<dim3(8 * S, 2), 256, 0, stream>>>(Bb, g1, b1, asim, tsim, adj, A);
    k_gemm2<<<MROWS / 128, 256, 0, stream>>>(A, W2T, Bb);
    k_gn2<<<dim3(8 * S, 2), 256, 0, stream>>>(Bb, g2, b2, asim, tsim, adj, out);
}

// Round 9
// 586.919 us; speedup vs baseline: 1.0221x; 1.0221x over previous
//
#include <hip/hip_runtime.h>

typedef __bf16 bf16;
typedef __bf16 bf16x4 __attribute__((ext_vector_type(4)));
typedef __bf16 bf16x8 __attribute__((ext_vector_type(8)));
typedef float f32x4 __attribute__((ext_vector_type(4)));
typedef float floatx4 __attribute__((ext_vector_type(4)));

#define S 96
#define DIN 768
#define DOUT 256
#define MROWS 73728  // 8*96*96

__device__ static inline void async16(const bf16* g, bf16* l) {
    __builtin_amdgcn_global_load_lds(
        (const __attribute__((address_space(1))) void*)g,
        (__attribute__((address_space(3))) void*)l,
        16, 0, 0);
}

// ---------------------------------------------------------------------------
// cast: fp32 -> bf16, grid-stride, 8 elems/thread/iter
// ---------------------------------------------------------------------------
__global__ __launch_bounds__(256) void k_cast(
    const float* __restrict__ in, bf16* __restrict__ out, long n)
{
    long i = ((long)blockIdx.x * 256 + threadIdx.x) * 8;
    long stride = (long)gridDim.x * 256 * 8;
    for (; i < n; i += stride) {
        f32x4 a = *(const f32x4*)&in[i];
        f32x4 b = *(const f32x4*)&in[i + 4];
        bf16x8 o;
#pragma unroll
        for (int j = 0; j < 4; ++j) { o[j] = (bf16)a[j]; o[4 + j] = (bf16)b[j]; }
        *(bf16x8*)&out[i] = o;
    }
}

// ---------------------------------------------------------------------------
// GEMM1: P0[M x 768] = X0 @ W1T^T (bf16). 256x256/BK=64, 8 waves, counted
// vmcnt, chunk-XOR swizzle. (r6 version — known-good at 135us.)
// ---------------------------------------------------------------------------
__global__ __launch_bounds__(512, 2) void k_gemm1(
    const bf16* __restrict__ Xm, const bf16* __restrict__ WT,
    bf16* __restrict__ Y)
{
    constexpr int K = 768, N = 768;
    constexpr int NTILE = K / 64;  // 12
    __shared__ __align__(16) bf16 As[2][256 * 64];
    __shared__ __align__(16) bf16 Bs[2][256 * 64];
    int t = threadIdx.x;
    int wg = blockIdx.x;
    wg = (wg & 7) * (gridDim.x >> 3) + (wg >> 3);  // 864 = 8*108: bijective
    int colBase = (wg % 3) * 256;                  // col fastest within XCD
    int rowBase = (wg / 3) * 256;
    int lane = t & 63, w = t >> 6;
    int quad = lane >> 4, l16 = lane & 15;
    int wr = w >> 2, wc = w & 3;                   // 2 x 4 waves

    floatx4 acc[8][4];
#pragma unroll
    for (int i = 0; i < 8; ++i)
#pragma unroll
        for (int j = 0; j < 4; ++j) acc[i][j] = (floatx4)0.f;

    int tr = t >> 3;
    int gc = (t & 7) ^ (tr & 7);
    const bf16* gA = Xm + (size_t)(rowBase + tr) * K + gc * 8;
    const bf16* gB = WT + (size_t)(colBase + tr) * K + gc * 8;
    int ldst = t * 8;

    auto stageA = [&](int b, int s, int kt) {
        async16(gA + (size_t)s * 64 * K + kt * 64, &As[b][s * 4096 + ldst]);
    };
    auto stageB = [&](int b, int s, int kt) {
        async16(gB + (size_t)s * 64 * K + kt * 64, &Bs[b][s * 4096 + ldst]);
    };

    // prologue: tile 0, order B0 B1 B2 B3 A0 A2 A1 A3
    stageB(0, 0, 0); stageB(0, 1, 0); stageB(0, 2, 0); stageB(0, 3, 0);
    stageA(0, 0, 0); stageA(0, 2, 0); stageA(0, 1, 0); stageA(0, 3, 0);
    asm volatile("s_waitcnt vmcnt(2)" ::: "memory");
    __builtin_amdgcn_s_barrier();

    int swz = l16 & 7;
    int cK0 = (quad ^ swz) * 8;
    int cK1 = ((quad + 4) ^ swz) * 8;

    for (int tt = 0; tt < NTILE; ++tt) {
        int cur = tt & 1;
        int nb = cur ^ 1;
        bool more = (tt + 1 < NTILE);
        const bf16* aB = &As[cur][(wr * 128 + l16) * 64];
        const bf16* bB = &Bs[cur][(wc * 64 + l16) * 64];
#pragma unroll
        for (int p = 0; p < 4; ++p) {
            const int ihalf = p & 1;
            const int co = (p >> 1) ? cK1 : cK0;
            bf16x8 af[4], bfr[4];
#pragma unroll
            for (int ii = 0; ii < 4; ++ii)
                af[ii] = *(const bf16x8*)(aB + (ihalf * 4 + ii) * 1024 + co);
#pragma unroll
            for (int j = 0; j < 4; ++j)
                bfr[j] = *(const bf16x8*)(bB + j * 1024 + co);
            if (more) {
                if (p == 0) { stageB(nb, 0, tt + 1); stageB(nb, 1, tt + 1); }
                if (p == 1) { stageB(nb, 2, tt + 1); stageB(nb, 3, tt + 1); }
                if (p == 2) { stageA(nb, 0, tt + 1); stageA(nb, 2, tt + 1); }
                if (p == 3) { stageA(nb, 1, tt + 1); stageA(nb, 3, tt + 1); }
            }
            __builtin_amdgcn_s_barrier();
            asm volatile("s_waitcnt lgkmcnt(0)" ::: "memory");
            __builtin_amdgcn_sched_barrier(0);
            __builtin_amdgcn_s_setprio(1);
#pragma unroll
            for (int ii = 0; ii < 4; ++ii)
#pragma unroll
                for (int j = 0; j < 4; ++j)
                    acc[ihalf * 4 + ii][j] = __builtin_amdgcn_mfma_f32_16x16x32_bf16(
                        af[ii], bfr[j], acc[ihalf * 4 + ii][j], 0, 0, 0);
            __builtin_amdgcn_s_setprio(0);
            if (p == 0) {
                if (more) asm volatile("s_waitcnt vmcnt(2)" ::: "memory");
                else      asm volatile("s_waitcnt vmcnt(0)" ::: "memory");
            }
            if (p == 3 && more) asm volatile("s_waitcnt vmcnt(2)" ::: "memory");
            __builtin_amdgcn_s_barrier();
        }
    }

#pragma unroll
    for (int i = 0; i < 8; ++i) {
#pragma unroll
        for (int r = 0; r < 4; ++r) {
            int row = rowBase + wr * 128 + i * 16 + quad * 4 + r;
            bf16* yp = Y + (size_t)row * N + colBase + wc * 64 + l16;
#pragma unroll
            for (int j = 0; j < 4; ++j)
                yp[j * 16] = (bf16)acc[i][j][r];
        }
    }
}

// ---------------------------------------------------------------------------
// gn1: h1 = relu(g1 * t5norm((2I+G')P0 + b1)). One (b,l,half) per block.
// Row split 512+256 -> per stream one bf16x8 (16B) + one bf16x4 (8B):
// 10 loads/row instead of 15, 2 stores instead of 3 (G13 widening).
// ---------------------------------------------------------------------------
__global__ __launch_bounds__(256) void k_gn1(
    const bf16* __restrict__ P, const float* __restrict__ G1,
    const float* __restrict__ B1, const float* __restrict__ Asim,
    const float* __restrict__ Tsim, const float* __restrict__ Adj,
    bf16* __restrict__ O)
{
    __shared__ float adjs[S];
    __shared__ float ts[S];
    __shared__ float diagf[DIN];
    __shared__ float g1s[DIN];
    __shared__ float b1s[DIN];
    int bx = blockIdx.x;
    bx = (bx & 7) * (gridDim.x >> 3) + (bx >> 3);  // 768 % 8 == 0
    int b = bx / S, l = bx % S;
    int tid = threadIdx.x;
    long row0 = (long)(b * S + l) * S;
    for (int i = tid; i < DIN; i += 256) { g1s[i] = G1[i]; b1s[i] = B1[i]; }
    if (tid < S) {
        adjs[tid] = Adj[(b * S + l) * S + tid];
        ts[tid]   = Tsim[b * S + tid];
        bf16x8 dv = *(const bf16x8*)&P[(row0 + l) * DIN + tid * 8];
#pragma unroll
        for (int j = 0; j < 8; ++j) diagf[tid * 8 + j] = (float)dv[j];
    }
    float a_up = (l > 0)     ? Asim[b * S + l - 1] : 0.f;
    float a_dn = (l < S - 1) ? Asim[b * S + l + 1] : 0.f;
    long du = (l > 0)     ? -(long)S * DIN : 0;
    long dd = (l < S - 1) ?  (long)S * DIN : 0;
    __syncthreads();

    int lane = tid & 63, wv = tid >> 6;
    int k0 = blockIdx.y * (S / 2);
    for (int k = k0 + wv; k < k0 + S / 2; k += 4) {
        float tl = (k > 0)     ? ts[k - 1] : 0.f;
        float tr = (k < S - 1) ? ts[k + 1] : 0.f;
        long  dl = (k > 0)     ? -(long)DIN : 0;
        long  dr = (k < S - 1) ?  (long)DIN : 0;
        float aj = adjs[k];
        const bf16* prow = P + (row0 + k) * DIN;
        bf16* orow = O + (row0 + k) * DIN;
        float v[12];
        float ss = 0.f;
        // segment A: 512 elems, 16B/lane
        {
            int col = lane * 8;
            const bf16* pc = prow + col;
            bf16x8 vc = *(const bf16x8*)pc;
            bf16x8 vl = *(const bf16x8*)(pc + dl);
            bf16x8 vr = *(const bf16x8*)(pc + dr);
            bf16x8 vu = *(const bf16x8*)(pc + du);
            bf16x8 vd = *(const bf16x8*)(pc + dd);
#pragma unroll
            for (int j = 0; j < 8; ++j) {
                float x = 2.f * (float)vc[j] + aj * diagf[col + j]
                        + tl * (float)vl[j] + tr * (float)vr[j]
                        + a_up * (float)vu[j] + a_dn * (float)vd[j]
                        + b1s[col + j];
                v[j] = x;
                ss += x * x;
            }
        }
        // segment B: remaining 256 elems, 8B/lane
        {
            int col = 512 + lane * 4;
            const bf16* pc = prow + col;
            bf16x4 vc = *(const bf16x4*)pc;
            bf16x4 vl = *(const bf16x4*)(pc + dl);
            bf16x4 vr = *(const bf16x4*)(pc + dr);
            bf16x4 vu = *(const bf16x4*)(pc + du);
            bf16x4 vd = *(const bf16x4*)(pc + dd);
#pragma unroll
            for (int j = 0; j < 4; ++j) {
                float x = 2.f * (float)vc[j] + aj * diagf[col + j]
                        + tl * (float)vl[j] + tr * (float)vr[j]
                        + a_up * (float)vu[j] + a_dn * (float)vd[j]
                        + b1s[col + j];
                v[8 + j] = x;
                ss += x * x;
            }
        }
        ss += __shfl_xor(ss, 1);
        ss += __shfl_xor(ss, 2);
        ss += __shfl_xor(ss, 4);
        ss += __shfl_xor(ss, 8);
        ss += __shfl_xor(ss, 16);
        ss += __shfl_xor(ss, 32);
        float inv = rsqrtf(ss * (1.f / DIN) + 1e-12f);
        {
            int col = lane * 8;
            bf16x8 o;
#pragma unroll
            for (int j = 0; j < 8; ++j) {
                float y = v[j] * g1s[col + j] * inv;
                o[j] = (bf16)(y > 0.f ? y : 0.f);
            }
            *(bf16x8*)&orow[col] = o;
        }
        {
            int col = 512 + lane * 4;
            bf16x4 o;
#pragma unroll
            for (int j = 0; j < 4; ++j) {
                float y = v[8 + j] * g1s[col + j] * inv;
                o[j] = (bf16)(y > 0.f ? y : 0.f);
            }
            *(bf16x4*)&orow[col] = o;
        }
    }
}

// ---------------------------------------------------------------------------
// GEMM2: P1[M x 256] = h1 @ W2T^T (bf16, plain — norm moved to gn2).
// 128 rows x 256 cols per block; 3-buf counted vmcnt.
// ---------------------------------------------------------------------------
__global__ __launch_bounds__(256, 2) void k_gemm2(
    const bf16* __restrict__ Xm, const bf16* __restrict__ WT,
    bf16* __restrict__ Y)
{
    constexpr int K = 768, N = 256;
    constexpr int NT = K / 32;  // 24
    __shared__ __align__(16) bf16 As[3][128 * 32];
    __shared__ __align__(16) bf16 Bs[3][256 * 32];
    int t = threadIdx.x;
    int rowBase = blockIdx.x * 128;
    int lane = t & 63, w = t >> 6;
    int quad = lane >> 4, l16 = lane & 15;
    int wr = w >> 1, wc = w & 1;

    floatx4 acc[4][8];
#pragma unroll
    for (int i = 0; i < 4; ++i)
#pragma unroll
        for (int j = 0; j < 8; ++j) acc[i][j] = (floatx4)0.f;

    int chunk = (t & 3) ^ ((t >> 3) & 3);
    const bf16* gA = Xm + (size_t)(rowBase + (t >> 2)) * K + chunk * 8;
    const bf16* gB = WT + (size_t)(t >> 2) * K + chunk * 8;
    int l8 = t * 8;

    auto stage = [&](int buf, int kk) {
        async16(gA + kk, &As[buf][l8]);
        async16(gA + kk + 64 * K, &As[buf][l8 + 2048]);
        async16(gB + kk, &Bs[buf][l8]);
        async16(gB + kk + 64 * K, &Bs[buf][l8 + 2048]);
        async16(gB + kk + 128 * K, &Bs[buf][l8 + 4096]);
        async16(gB + kk + 192 * K, &Bs[buf][l8 + 6144]);
    };

    stage(0, 0);
    stage(1, 32);
    for (int tt = 0; tt < NT; ++tt) {
        if (tt + 1 < NT) asm volatile("s_waitcnt vmcnt(6)" ::: "memory");
        else             asm volatile("s_waitcnt vmcnt(0)" ::: "memory");
        __builtin_amdgcn_s_barrier();
        int cur = tt % 3;
        bf16x8 af[4], bfr[8];
#pragma unroll
        for (int i = 0; i < 4; ++i) {
            int ra = wr * 64 + i * 16 + l16;
            af[i] = *(const bf16x8*)&As[cur][ra * 32 + (quad ^ ((ra >> 1) & 3)) * 8];
        }
#pragma unroll
        for (int j = 0; j < 8; ++j) {
            int rb = wc * 128 + j * 16 + l16;
            bfr[j] = *(const bf16x8*)&Bs[cur][rb * 32 + (quad ^ ((rb >> 1) & 3)) * 8];
        }
        if (tt + 2 < NT) stage((tt + 2) % 3, (tt + 2) * 32);
#pragma unroll
        for (int i = 0; i < 4; ++i)
#pragma unroll
            for (int j = 0; j < 8; ++j)
                acc[i][j] = __builtin_amdgcn_mfma_f32_16x16x32_bf16(
                    af[i], bfr[j], acc[i][j], 0, 0, 0);
    }

#pragma unroll
    for (int i = 0; i < 4; ++i) {
#pragma unroll
        for (int r = 0; r < 4; ++r) {
            int row = rowBase + wr * 64 + i * 16 + quad * 4 + r;
            bf16* yp = Y + (size_t)row * N + wc * 128 + l16;
#pragma unroll
            for (int j = 0; j < 8; ++j)
                yp[j * 16] = (bf16)acc[i][j][r];
        }
    }
}

// ---------------------------------------------------------------------------
// gn2: out = relu(g2 * t5norm((2I+G')P1 + b2)), fp32 out. D=256: 4 f32/lane.
// ---------------------------------------------------------------------------
__global__ __launch_bounds__(256) void k_gn2(
    const bf16* __restrict__ P, const float* __restrict__ G2,
    const float* __restrict__ B2, const float* __restrict__ Asim,
    const float* __restrict__ Tsim, const float* __restrict__ Adj,
    float* __restrict__ O)
{
    __shared__ float adjs[S];
    __shared__ float ts[S];
    __shared__ float diagf[DOUT];
    __shared__ float g2s[DOUT];
    __shared__ float b2s[DOUT];
    int bx = blockIdx.x;
    bx = (bx & 7) * (gridDim.x >> 3) + (bx >> 3);
    int b = bx / S, l = bx % S;
    int tid = threadIdx.x;
    long row0 = (long)(b * S + l) * S;
    if (tid < DOUT) { g2s[tid] = G2[tid]; b2s[tid] = B2[tid]; }
    if (tid < S) {
        adjs[tid] = Adj[(b * S + l) * S + tid];
        ts[tid]   = Tsim[b * S + tid];
    }
    if (tid < 32) {
        bf16x8 dv = *(const bf16x8*)&P[(row0 + l) * DOUT + tid * 8];
#pragma unroll
        for (int j = 0; j < 8; ++j) diagf[tid * 8 + j] = (float)dv[j];
    }
    float a_up = (l > 0)     ? Asim[b * S + l - 1] : 0.f;
    float a_dn = (l < S - 1) ? Asim[b * S + l + 1] : 0.f;
    long du = (l > 0)     ? -(long)S * DOUT : 0;
    long dd = (l < S - 1) ?  (long)S * DOUT : 0;
    __syncthreads();

    int lane = tid & 63, wv = tid >> 6;
    int k0 = blockIdx.y * (S / 2);
    for (int k = k0 + wv; k < k0 + S / 2; k += 4) {
        float tl = (k > 0)     ? ts[k - 1] : 0.f;
        float tr = (k < S - 1) ? ts[k + 1] : 0.f;
        long  dl = (k > 0)     ? -(long)DOUT : 0;
        long  dr = (k < S - 1) ?  (long)DOUT : 0;
        float aj = adjs[k];
        const bf16* prow = P + (row0 + k) * DOUT;
        float* orow = O + (row0 + k) * DOUT;
        int col = lane * 4;
        const bf16* pc = prow + col;
        bf16x4 vc = *(const bf16x4*)pc;
        bf16x4 vl = *(const bf16x4*)(pc + dl);
        bf16x4 vr = *(const bf16x4*)(pc + dr);
        bf16x4 vu = *(const bf16x4*)(pc + du);
        bf16x4 vd = *(const bf16x4*)(pc + dd);
        float v[4];
        float ss = 0.f;
#pragma unroll
        for (int j = 0; j < 4; ++j) {
            float x = 2.f * (float)vc[j] + aj * diagf[col + j]
                    + tl * (float)vl[j] + tr * (float)vr[j]
                    + a_up * (float)vu[j] + a_dn * (float)vd[j]
                    + b2s[col + j];
            v[j] = x;
            ss += x * x;
        }
        ss += __shfl_xor(ss, 1);
        ss += __shfl_xor(ss, 2);
        ss += __shfl_xor(ss, 4);
        ss += __shfl_xor(ss, 8);
        ss += __shfl_xor(ss, 16);
        ss += __shfl_xor(ss, 32);
        float inv = rsqrtf(ss * (1.f / DOUT) + 1e-12f);
        f32x4 o;
#pragma unroll
        for (int j = 0; j < 4; ++j) {
            float y = v[j] * g2s[col + j] * inv;
            o[j] = y > 0.f ? y : 0.f;
        }
        *(f32x4*)&orow[col] = o;
    }
}

// tiled transpose + cast: in fp32 [R][C] -> out bf16 [C][R]; grid (C/32, R/32)
__global__ __launch_bounds__(256) void k_castT(
    const float* __restrict__ in, bf16* __restrict__ out, int R, int C)
{
    __shared__ float tile[32][33];
    int lx = threadIdx.x & 31, ly = threadIdx.x >> 5;
    int c0 = blockIdx.x * 32, r0 = blockIdx.y * 32;
#pragma unroll
    for (int k = 0; k < 4; ++k)
        tile[ly + 8 * k][lx] = in[(size_t)(r0 + ly + 8 * k) * C + c0 + lx];
    __syncthreads();
#pragma unroll
    for (int k = 0; k < 4; ++k)
        out[(size_t)(c0 + ly + 8 * k) * R + r0 + lx] = (bf16)tile[lx][ly + 8 * k];
}

// ---------------------------------------------------------------------------
extern "C" void kernel_launch(void* const* d_in, const int* in_sizes, int n_in,
                              void* d_out, int out_size, void* d_ws, size_t ws_size,
                              hipStream_t stream)
{
    const float* table = (const float*)d_in[0];
    const float* asim  = (const float*)d_in[1];
    const float* tsim  = (const float*)d_in[2];
    const float* adj   = (const float*)d_in[3];
    const float* W1    = (const float*)d_in[4];
    const float* b1    = (const float*)d_in[5];
    const float* g1    = (const float*)d_in[6];
    const float* W2    = (const float*)d_in[7];
    const float* b2    = (const float*)d_in[8];
    const float* g2    = (const float*)d_in[9];
    float* out = (float*)d_out;

    char* ws = (char*)d_ws;
    const size_t SZ_X = (size_t)MROWS * DIN * 2;          // 113246208 bytes
    bf16*  A    = (bf16*)ws;                               // X0 bf16, later h1
    bf16*  Bb   = (bf16*)(ws + SZ_X);                      // P0, later P1
    bf16*  W1T  = (bf16*)(ws + 2 * SZ_X);
    bf16*  W2T  = (bf16*)(ws + 2 * SZ_X + 1179648);

    k_castT<<<dim3(DIN / 32, DIN / 32), 256, 0, stream>>>(W1, W1T, DIN, DIN);
    k_castT<<<dim3(DOUT / 32, DIN / 32), 256, 0, stream>>>(W2, W2T, DIN, DOUT);

    k_cast<<<2048, 256, 0, stream>>>(table, A, (long)MROWS * DIN);
    k_gemm1<<<dim3((DIN / 256) * (MROWS / 256)), 512, 0, stream>>>(A, W1T, Bb);
    k_gn1<<<dim3(8 * S, 2), 256, 0, stream>>>(Bb, g1, b1, asim, tsim, adj, A);
    k_gemm2<<<MROWS / 128, 256, 0, stream>>>(A, W2T, Bb);
    k_gn2<<<dim3(8 * S, 2), 256, 0, stream>>>(Bb, g2, b2, asim, tsim, adj, out);
}